// Round 4
// baseline (250.578 us; speedup 1.0000x reference)
//
#include <hip/hip_runtime.h>

#define CIN 128
#define CH 256
#define COUT 128
#define BN_EPS 1e-5f

typedef __attribute__((ext_vector_type(8))) short bf16x8;
typedef __attribute__((ext_vector_type(4))) float f32x4;

// float -> bf16 (round-to-nearest-even), raw short
__device__ __forceinline__ short f2bf(float x) {
    unsigned u = __float_as_uint(x);
    unsigned r = (u + 0x7fffu + ((u >> 16) & 1u)) >> 16;
    return (short)r;
}
__device__ __forceinline__ float bf2f(short h) {
    return __uint_as_float(((unsigned)(unsigned short)h) << 16);
}

// gather one row's edge list into acc[8] (channels c*8..c*8+7), xb stride 128.
// csr entry: .x = fp32 bits of w (dinv[src]*dinv[dst]), .y = src index.
__device__ __forceinline__ void gather_edges(const short* __restrict__ xb,
                                             const uint2* __restrict__ csr,
                                             int e0, int e1, int c,
                                             float* acc) {
    int e = e0;
    for (; e + 7 < e1; e += 8) {
        uint2 ew[8];
        #pragma unroll
        for (int i = 0; i < 8; ++i) ew[i] = csr[e + i];
        bf16x8 x[8];
        #pragma unroll
        for (int i = 0; i < 8; ++i) x[i] = *(const bf16x8*)(xb + (size_t)ew[i].y * 128 + c * 8);
        #pragma unroll
        for (int i = 0; i < 8; ++i) {
            float w = __uint_as_float(ew[i].x);
            #pragma unroll
            for (int j = 0; j < 8; ++j) acc[j] = fmaf(w, bf2f(x[i][j]), acc[j]);
        }
    }
    for (; e + 3 < e1; e += 4) {
        uint2 ew[4];
        #pragma unroll
        for (int i = 0; i < 4; ++i) ew[i] = csr[e + i];
        bf16x8 x[4];
        #pragma unroll
        for (int i = 0; i < 4; ++i) x[i] = *(const bf16x8*)(xb + (size_t)ew[i].y * 128 + c * 8);
        #pragma unroll
        for (int i = 0; i < 4; ++i) {
            float w = __uint_as_float(ew[i].x);
            #pragma unroll
            for (int j = 0; j < 8; ++j) acc[j] = fmaf(w, bf2f(x[i][j]), acc[j]);
        }
    }
    for (; e < e1; ++e) {
        uint2 ew = csr[e];
        float w = __uint_as_float(ew.x);
        bf16x8 x0 = *(const bf16x8*)(xb + (size_t)ew.y * 128 + c * 8);
        #pragma unroll
        for (int j = 0; j < 8; ++j) acc[j] = fmaf(w, bf2f(x0[j]), acc[j]);
    }
}

// count in-degree; record each edge's rank within its dst bucket
__global__ void k_deg(const int* __restrict__ dst, int* __restrict__ degi,
                      unsigned short* __restrict__ rank, int E) {
    int e = blockIdx.x * 256 + threadIdx.x;
    if (e < E) rank[e] = (unsigned short)atomicAdd(&degi[dst[e]], 1);
}

// block sums of degi + fused dinv = rsqrt(deg+1) + degree histogram (for sort)
__global__ void k_scan1(const int* __restrict__ degi, float* __restrict__ dinv,
                        int* __restrict__ blocksum, int* __restrict__ hist, int N) {
    __shared__ int s[256];
    __shared__ int h[256];
    int tid = threadIdx.x;
    h[tid] = 0;
    int i = blockIdx.x * 256 + tid;
    int v = (i < N) ? degi[i] : 0;
    if (i < N) dinv[i] = rsqrtf((float)(v + 1));
    s[tid] = v;
    __syncthreads();
    if (i < N) atomicAdd(&h[v > 255 ? 255 : v], 1);
    for (int st = 128; st > 0; st >>= 1) {
        if (tid < st) s[tid] += s[tid + st];
        __syncthreads();
    }
    if (tid == 0) blocksum[blockIdx.x] = s[0];
    int hv = h[tid];
    if (hv) atomicAdd(&hist[tid], hv);
}

// per-element exclusive scan; every block redundantly scans blocksum in LDS. nb <= 256.
// block 0 additionally exclusive-scans the degree histogram -> histbase.
__global__ void k_scan3(const int* __restrict__ degi, const int* __restrict__ blocksum,
                        int nb, int* __restrict__ rowstart,
                        const int* __restrict__ hist, int* __restrict__ histbase,
                        int N, int E) {
    __shared__ int sb[256];
    __shared__ int s[256];
    int tid = threadIdx.x;
    int bv = (tid < nb) ? blocksum[tid] : 0;
    sb[tid] = bv;
    __syncthreads();
    for (int st = 1; st < 256; st <<= 1) {
        int t = (tid >= st) ? sb[tid - st] : 0;
        __syncthreads();
        sb[tid] += t;
        __syncthreads();
    }
    int boff = (blockIdx.x == 0) ? 0 : sb[blockIdx.x - 1];

    int i = blockIdx.x * 256 + tid;
    int v = (i < N) ? degi[i] : 0;
    s[tid] = v;
    __syncthreads();
    for (int st = 1; st < 256; st <<= 1) {
        int t = (tid >= st) ? s[tid - st] : 0;
        __syncthreads();
        s[tid] += t;
        __syncthreads();
    }
    if (i < N) rowstart[i] = s[tid] - v + boff;
    if (blockIdx.x == 0 && tid == 0) rowstart[N] = E;

    if (blockIdx.x == 0) {
        __shared__ int hh[256];
        int own = hist[tid];
        hh[tid] = own;
        __syncthreads();
        for (int st = 1; st < 256; st <<= 1) {
            int t = (tid >= st) ? hh[tid - st] : 0;
            __syncthreads();
            hh[tid] += t;
            __syncthreads();
        }
        histbase[tid] = hh[tid] - own;   // exclusive
    }
}

// CSR fill with precomputed edge weights (edge blocks) + degree-sort scatter
// (node blocks, two-level counting: LDS rank + 1 global atomic/bucket/block).
__global__ void k_fillperm(const int* __restrict__ src, const int* __restrict__ dst,
                           const unsigned short* __restrict__ rank,
                           const int* __restrict__ rowstart,
                           const float* __restrict__ dinv,
                           uint2* __restrict__ csr,
                           const int* __restrict__ degi,
                           const int* __restrict__ histbase, int* __restrict__ histcnt,
                           int* __restrict__ perm, int E, int N, int nbE) {
    __shared__ int h[256];
    __shared__ int base[256];
    int tid = threadIdx.x;
    if ((int)blockIdx.x < nbE) {
        int e = blockIdx.x * 256 + tid;
        if (e < E) {
            int d = dst[e];
            int s = src[e];
            int pos = rowstart[d] + (int)rank[e];
            uint2 ev;
            ev.x = __float_as_uint(dinv[s] * dinv[d]);
            ev.y = (unsigned)s;
            csr[pos] = ev;
        }
        return;
    }
    int i0 = ((int)blockIdx.x - nbE) * 1024;
    h[tid] = 0;
    __syncthreads();
    int d[4], lr[4];
    #pragma unroll
    for (int k = 0; k < 4; ++k) {
        int i = i0 + k * 256 + tid;
        if (i < N) {
            int dd = degi[i];
            if (dd > 255) dd = 255;
            d[k] = dd;
            lr[k] = atomicAdd(&h[dd], 1);     // LDS atomic: local rank
        } else {
            d[k] = -1;
        }
    }
    __syncthreads();
    int cnt = h[tid];
    if (cnt > 0) base[tid] = atomicAdd(&histcnt[tid], cnt);   // 1 global atomic / bucket / block
    __syncthreads();
    #pragma unroll
    for (int k = 0; k < 4; ++k) {
        if (d[k] >= 0)
            perm[histbase[d[k]] + base[d[k]] + lr[k]] = i0 + k * 256 + tid;
    }
}

// fused prep: W swizzle -> bf16 fragments, features -> bf16, zero degi/stats/hist
__global__ void k_prep(const float* __restrict__ W1, const float* __restrict__ W2,
                       short* __restrict__ W1sw, short* __restrict__ W2sw,
                       const float4* __restrict__ nf, short4* __restrict__ nfb,
                       int* __restrict__ degi, float* __restrict__ stats,
                       int* __restrict__ hist, int n4, int N) {
    int t = blockIdx.x * 256 + threadIdx.x;
    if (t < 32768) {                 // W1 [128][256]
        if (t < 512) stats[t] = 0.0f;
        else if (t < 1024) hist[t - 512] = 0;   // hist[256] ++ histcnt[256]
        int n = t >> 7, kk = t & 127;
        float v = W1[kk * 256 + n];
        int t16 = n >> 4, m = n & 15;
        int ks = kk >> 5, q = (kk >> 3) & 3, j = kk & 7;
        W1sw[(t16 * 4 + ks) * 512 + (q * 16 + m) * 8 + j] = f2bf(v);
    } else if (t < 65536) {          // W2 [256][128]
        int u = t - 32768;
        int n = u >> 8, kk = u & 255;
        float v = W2[kk * 128 + n];
        int t16 = n >> 4, m = n & 15;
        int ks = kk >> 5, q = (kk >> 3) & 3, j = kk & 7;
        W2sw[(t16 * 8 + ks) * 512 + (q * 16 + m) * 8 + j] = f2bf(v);
    } else {
        int u = t - 65536;
        if (u < n4) {
            float4 v = nf[u];
            short4 s;
            s.x = f2bf(v.x); s.y = f2bf(v.y); s.z = f2bf(v.z); s.w = f2bf(v.w);
            nfb[u] = s;
        } else {
            int u2 = u - n4;
            if (u2 < N) degi[u2] = 0;
        }
    }
}

// Layer 1 fused: gather(S @ nfb) for 64 rows straight into the LDS A-tile,
// then x1 = A @ W1 + b1 with BN-stat accumulation via atomics.
// STRIDED block->row assignment: block b, local row k takes sorted position
// k*nb + b -> every block's 64 rows sample the whole degree distribution
// (equal per-block work; grid is a single scheduling round so block balance
// IS the makespan). Local k stays monotone in degree -> each wave-pass's
// row-groups remain degree-matched (no intra-wave divergence).
__global__ __launch_bounds__(512, 4) void k_gemm1g(
        const short* __restrict__ xb, const int* __restrict__ rowstart,
        const uint2* __restrict__ csr, const float* __restrict__ dinv,
        const int* __restrict__ perm, const short* __restrict__ Bsw,
        const float* __restrict__ bias, short* __restrict__ C,
        float* __restrict__ stats, int M) {
    constexpr int K = CIN, NOUT = CH;
    constexpr int CT = NOUT / 128;   // 2 col16-tiles per wave (8 waves)
    constexpr int KS = K / 32;       // 4
    constexpr int KP = K + 8;
    constexpr int LROW = NOUT + 8;
    constexpr int LSZ = (64 * KP > 64 * LROW) ? 64 * KP : 64 * LROW;
    __shared__ __align__(16) short lds[LSZ];
    __shared__ int prow[64];
    int tid = threadIdx.x;
    int wave = tid >> 6;             // 0..7
    int lane = tid & 63;
    int m = lane & 15;
    int q = lane >> 4;
    int nb = gridDim.x;
    int bid = blockIdx.x;
    if (tid < 64) {
        int spos = tid * nb + bid;       // strided sorted position
        if (spos >= M) spos = M - 1;     // dup of cheapest row; excluded from stats/C
        prow[tid] = perm[M - 1 - spos];  // descending degree in local k
    }
    __syncthreads();

    // gather phase: 2 passes x 32 rows, 16 lanes (8ch each) per row
    int c = tid & 15;
    int g = tid >> 4;                // 0..31
    #pragma unroll
    for (int p = 0; p < 2; ++p) {
        int rl = p * 32 + g;
        int r = prow[rl];
        float di = dinv[r];
        float w0 = di * di;
        bf16x8 sv = *(const bf16x8*)(xb + (size_t)r * 128 + c * 8);
        float acc[8];
        #pragma unroll
        for (int j = 0; j < 8; ++j) acc[j] = bf2f(sv[j]) * w0;
        gather_edges(xb, csr, rowstart[r], rowstart[r + 1], c, acc);
        bf16x8 h;
        #pragma unroll
        for (int j = 0; j < 8; ++j) h[j] = f2bf(acc[j]);
        *(bf16x8*)(lds + rl * KP + c * 8) = h;
    }
    __syncthreads();

    f32x4 acc4[4][CT];
    #pragma unroll
    for (int rt = 0; rt < 4; ++rt)
        #pragma unroll
        for (int ct = 0; ct < CT; ++ct)
            acc4[rt][ct] = (f32x4){0.f, 0.f, 0.f, 0.f};

    #pragma unroll
    for (int ks = 0; ks < KS; ++ks) {
        bf16x8 bh[CT];
        #pragma unroll
        for (int ct = 0; ct < CT; ++ct)
            bh[ct] = *(const bf16x8*)(Bsw + (size_t)((wave * CT + ct) * KS + ks) * 512 + lane * 8);
        bf16x8 af[4];
        #pragma unroll
        for (int rt = 0; rt < 4; ++rt)
            af[rt] = *(const bf16x8*)(lds + (rt * 16 + m) * KP + ks * 32 + q * 8);
        #pragma unroll
        for (int ct = 0; ct < CT; ++ct)
            #pragma unroll
            for (int rt = 0; rt < 4; ++rt)
                acc4[rt][ct] = __builtin_amdgcn_mfma_f32_16x16x32_bf16(af[rt], bh[ct], acc4[rt][ct], 0, 0, 0);
    }
    __syncthreads();   // A-tile reads done; reuse LDS for epilogue

    #pragma unroll
    for (int ct = 0; ct < CT; ++ct) {
        int col = wave * 32 + ct * 16 + m;
        float bv = bias[col];
        float s = 0.f, sq = 0.f;
        #pragma unroll
        for (int rt = 0; rt < 4; ++rt) {
            #pragma unroll
            for (int r = 0; r < 4; ++r) {
                int lrow = rt * 16 + q * 4 + r;
                float v = acc4[rt][ct][r] + bv;
                if (lrow * nb + bid < M) { s += v; sq = fmaf(v, v, sq); }
                lds[lrow * LROW + col] = f2bf(v);
            }
        }
        s += __shfl_xor(s, 16, 64);
        s += __shfl_xor(s, 32, 64);
        sq += __shfl_xor(sq, 16, 64);
        sq += __shfl_xor(sq, 32, 64);
        if (lane < 16) {
            unsafeAtomicAdd(&stats[col], s);
            unsafeAtomicAdd(&stats[256 + col], sq);
        }
    }
    __syncthreads();
    constexpr int CPR = NOUT / 8;       // 32
    #pragma unroll
    for (int i = 0; i < (64 * CPR) / 512; ++i) {
        int idx = i * 512 + tid;
        int row = idx / CPR;
        int ch = idx % CPR;
        if (row * nb + bid < M)
            *(bf16x8*)(C + (size_t)prow[row] * NOUT + ch * 8) =
                *(const bf16x8*)(lds + row * LROW + ch * 8);
    }
}

__device__ __forceinline__ bf16x8 bnrelu8(bf16x8 raw, const float* __restrict__ scsh, int c) {
    float4 sc0 = *(const float4*)(scsh + c);
    float4 sc1 = *(const float4*)(scsh + c + 4);
    float4 sh0 = *(const float4*)(scsh + 256 + c);
    float4 sh1 = *(const float4*)(scsh + 256 + c + 4);
    bf16x8 o;
    o[0] = f2bf(fmaxf(fmaf(bf2f(raw[0]), sc0.x, sh0.x), 0.f));
    o[1] = f2bf(fmaxf(fmaf(bf2f(raw[1]), sc0.y, sh0.y), 0.f));
    o[2] = f2bf(fmaxf(fmaf(bf2f(raw[2]), sc0.z, sh0.z), 0.f));
    o[3] = f2bf(fmaxf(fmaf(bf2f(raw[3]), sc0.w, sh0.w), 0.f));
    o[4] = f2bf(fmaxf(fmaf(bf2f(raw[4]), sc1.x, sh1.x), 0.f));
    o[5] = f2bf(fmaxf(fmaf(bf2f(raw[5]), sc1.y, sh1.y), 0.f));
    o[6] = f2bf(fmaxf(fmaf(bf2f(raw[6]), sc1.z, sh1.z), 0.f));
    o[7] = f2bf(fmaxf(fmaf(bf2f(raw[7]), sc1.w, sh1.w), 0.f));
    return o;
}

// Layer 2 GEMM: y = relu(bn(x1)) @ W2. BN scale/shift derived from stats in
// each block (2KB LDS, trivial redundant compute).
__global__ __launch_bounds__(256, 4) void k_gemm2(
        const short* __restrict__ A, const short* __restrict__ Bsw,
        const float* __restrict__ stats, const float* __restrict__ gamma,
        const float* __restrict__ beta, short* __restrict__ C, int M) {
    constexpr int K = CH, NOUT = COUT;
    constexpr int CT = NOUT / 64;    // 2
    constexpr int KS = K / 32;       // 8
    constexpr int KP = K + 8;
    constexpr int LROW = NOUT + 8;
    constexpr int LSZ = (64 * KP > 64 * LROW) ? 64 * KP : 64 * LROW;
    __shared__ __align__(16) short lds[LSZ];
    __shared__ float scsh[512];
    int tid = threadIdx.x;
    int wave = tid >> 6;
    int lane = tid & 63;
    int m = lane & 15;
    int q = lane >> 4;
    int row0 = blockIdx.x * 64;

    if (tid < 256) {
        float invN = 1.0f / (float)M;
        float mean = stats[tid] * invN;
        float var = fmaxf(stats[256 + tid] * invN - mean * mean, 0.f);
        float inv = rsqrtf(var + BN_EPS);
        float sc = gamma[tid] * inv;
        scsh[tid] = sc;
        scsh[256 + tid] = fmaf(-mean, sc, beta[tid]);
    }
    __syncthreads();

    constexpr int CPRA = K / 8;      // 32
    #pragma unroll
    for (int i = 0; i < (64 * CPRA) / 256; ++i) {
        int idx = i * 256 + tid;
        int r = idx / CPRA, cc = idx % CPRA;
        int gr = row0 + r;
        if (gr >= M) gr = M - 1;
        bf16x8 v = *(const bf16x8*)(A + (size_t)gr * K + cc * 8);
        v = bnrelu8(v, scsh, cc * 8);
        *(bf16x8*)(lds + r * KP + cc * 8) = v;
    }
    __syncthreads();

    f32x4 acc[4][CT];
    #pragma unroll
    for (int rt = 0; rt < 4; ++rt)
        #pragma unroll
        for (int ct = 0; ct < CT; ++ct)
            acc[rt][ct] = (f32x4){0.f, 0.f, 0.f, 0.f};

    #pragma unroll
    for (int ks = 0; ks < KS; ++ks) {
        bf16x8 bh[CT];
        #pragma unroll
        for (int ct = 0; ct < CT; ++ct)
            bh[ct] = *(const bf16x8*)(Bsw + (size_t)((wave * CT + ct) * KS + ks) * 512 + lane * 8);
        bf16x8 af[4];
        #pragma unroll
        for (int rt = 0; rt < 4; ++rt)
            af[rt] = *(const bf16x8*)(lds + (rt * 16 + m) * KP + ks * 32 + q * 8);
        #pragma unroll
        for (int ct = 0; ct < CT; ++ct)
            #pragma unroll
            for (int rt = 0; rt < 4; ++rt)
                acc[rt][ct] = __builtin_amdgcn_mfma_f32_16x16x32_bf16(af[rt], bh[ct], acc[rt][ct], 0, 0, 0);
    }
    __syncthreads();

    #pragma unroll
    for (int ct = 0; ct < CT; ++ct) {
        int col = wave * (NOUT / 4) + ct * 16 + m;
        #pragma unroll
        for (int rt = 0; rt < 4; ++rt) {
            #pragma unroll
            for (int r = 0; r < 4; ++r) {
                int lrow = rt * 16 + q * 4 + r;
                lds[lrow * LROW + col] = f2bf(acc[rt][ct][r]);
            }
        }
    }
    __syncthreads();
    constexpr int CPR = NOUT / 8;    // 16
    #pragma unroll
    for (int i = 0; i < (64 * CPR) / 256; ++i) {
        int idx = i * 256 + tid;
        int row = idx / CPR;
        int ch = idx % CPR;
        if (row0 + row < M)
            *(bf16x8*)(C + (size_t)(row0 + row) * NOUT + ch * 8) =
                *(const bf16x8*)(lds + row * LROW + ch * 8);
    }
}

// final gather: out = S @ y + b2, fp32 output, degree-sorted row order
// (3125 blocks, descending degree = SPT schedule; many rounds -> balanced)
__global__ __launch_bounds__(256) void k_gather1(
        const short* __restrict__ yb, const int* __restrict__ rowstart,
        const uint2* __restrict__ csr, const float* __restrict__ dinv,
        const int* __restrict__ perm, const float* __restrict__ bias,
        float* __restrict__ out, int N) {
    int t = blockIdx.x * 256 + threadIdx.x;
    int sp = t >> 4;
    int c = t & 15;
    if (sp >= N) return;
    int r = perm[N - 1 - sp];        // descending degree
    float di = dinv[r];
    float w0 = di * di;
    bf16x8 sv = *(const bf16x8*)(yb + (size_t)r * 128 + c * 8);
    float acc[8];
    #pragma unroll
    for (int j = 0; j < 8; ++j) acc[j] = bf2f(sv[j]) * w0;
    gather_edges(yb, csr, rowstart[r], rowstart[r + 1], c, acc);
    float4 b0 = *(const float4*)(bias + c * 8);
    float4 b1 = *(const float4*)(bias + c * 8 + 4);
    float4 o0 = make_float4(acc[0] + b0.x, acc[1] + b0.y, acc[2] + b0.z, acc[3] + b0.w);
    float4 o1 = make_float4(acc[4] + b1.x, acc[5] + b1.y, acc[6] + b1.z, acc[7] + b1.w);
    *(float4*)(out + (size_t)r * 128 + c * 8) = o0;
    *(float4*)(out + (size_t)r * 128 + c * 8 + 4) = o1;
}

extern "C" void kernel_launch(void* const* d_in, const int* in_sizes, int n_in,
                              void* d_out, int out_size, void* d_ws, size_t ws_size,
                              hipStream_t stream) {
    const float* nf    = (const float*)d_in[0];
    const int*   ei    = (const int*)d_in[1];
    const float* W1    = (const float*)d_in[2];
    const float* b1    = (const float*)d_in[3];
    const float* gamma = (const float*)d_in[4];
    const float* beta  = (const float*)d_in[5];
    const float* W2    = (const float*)d_in[6];
    const float* b2    = (const float*)d_in[7];
    float* out = (float*)d_out;

    const int N = in_sizes[0] / CIN;      // 50000
    const int E = in_sizes[1] / 2;        // 800000
    const int* src = ei;
    const int* dst = ei + E;

    const int nb1 = (N + 63) / 64;        // gemm row-blocks (782)

    char* ws = (char*)d_ws;
    auto align256 = [](size_t x) { return (x + 255) & ~(size_t)255; };
    size_t off = 0;
    int*   degi = (int*)(ws + off);      off += align256((size_t)N * 4);
    float* stats = (float*)(ws + off);   off += align256(512 * 4);
    float* dinv = (float*)(ws + off);    off += align256((size_t)N * 4);
    int*   rowstart = (int*)(ws + off);  off += align256((size_t)(N + 1) * 4);
    int*   blocksum = (int*)(ws + off);  off += align256(256 * 4);
    int*   hist = (int*)(ws + off);      off += align256(512 * 4);    // hist + histcnt
    int*   histbase = (int*)(ws + off);  off += align256(256 * 4);
    int*   perm = (int*)(ws + off);      off += align256((size_t)N * 4);
    short* W1sw = (short*)(ws + off);    off += align256(32768 * 2);
    short* W2sw = (short*)(ws + off);    off += align256(32768 * 2);
    unsigned short* rank = (unsigned short*)(ws + off); off += align256((size_t)E * 2);
    uint2* csr = (uint2*)(ws + off);     off += align256((size_t)E * 8);   // packed {w, src}
    short* nfb = (short*)(ws + off);     off += align256((size_t)N * CIN * 2);
    short* x1b = (short*)(ws + off);     off += align256((size_t)N * CH * 2);
    short* yb = (short*)(ws + off);      off += align256((size_t)N * COUT * 2);

    int nbN = (N + 255) / 256;
    int nbE = (E + 255) / 256;            // 3125 (E % 256 == 0)
    int nbP = (N + 1023) / 1024;          // 49 node-blocks for perm build
    int n4 = N * 32;

    // prep: weight swizzle + feature cast + zero degi/stats/hist
    k_prep<<<(65536 + n4 + N + 255) / 256, 256, 0, stream>>>(
        W1, W2, W1sw, W2sw, (const float4*)nf, (short4*)nfb, degi, stats, hist, n4, N);

    // degree/rank -> dinv + histogram -> rowstart + histbase -> CSR fill + perm
    k_deg<<<nbE, 256, 0, stream>>>(dst, degi, rank, E);
    k_scan1<<<nbN, 256, 0, stream>>>(degi, dinv, blocksum, hist, N);
    k_scan3<<<nbN, 256, 0, stream>>>(degi, blocksum, nbN, rowstart, hist, histbase, N, E);
    k_fillperm<<<nbE + nbP, 256, 0, stream>>>(
        src, dst, rank, rowstart, dinv, csr, degi, histbase, hist + 256, perm, E, N, nbE);

    // layer 1: fused gather + GEMM + bias + BN-stat atomics (strided balance)
    k_gemm1g<<<nb1, 512, 0, stream>>>(nfb, rowstart, csr, dinv, perm, W1sw, b1, x1b, stats, N);

    // layer 2: BN+ReLU (inline from stats) + GEMM
    k_gemm2<<<nb1, 256, 0, stream>>>(x1b, W2sw, stats, gamma, beta, yb, N);

    // out = S @ y + b2
    k_gather1<<<(N * 16 + 255) / 256, 256, 0, stream>>>(
        yb, rowstart, csr, dinv, perm, b2, out, N);
}

// Round 5
// 240.230 us; speedup vs baseline: 1.0431x; 1.0431x over previous
//
#include <hip/hip_runtime.h>

#define CIN 128
#define CH 256
#define COUT 128
#define BN_EPS 1e-5f

typedef __attribute__((ext_vector_type(8))) short bf16x8;
typedef __attribute__((ext_vector_type(4))) float f32x4;

// float -> bf16 (round-to-nearest-even), raw short
__device__ __forceinline__ short f2bf(float x) {
    unsigned u = __float_as_uint(x);
    unsigned r = (u + 0x7fffu + ((u >> 16) & 1u)) >> 16;
    return (short)r;
}
__device__ __forceinline__ float bf2f(short h) {
    return __uint_as_float(((unsigned)(unsigned short)h) << 16);
}

// gather one row's edge list into acc[8] (channels c*8..c*8+7), xb stride 128.
// csr entry: .x = fp32 bits of w (dinv[src]*dinv[dst]), .y = src index.
__device__ __forceinline__ void gather_edges(const short* __restrict__ xb,
                                             const uint2* __restrict__ csr,
                                             int e0, int e1, int c,
                                             float* acc) {
    int e = e0;
    for (; e + 7 < e1; e += 8) {
        uint2 ew[8];
        #pragma unroll
        for (int i = 0; i < 8; ++i) ew[i] = csr[e + i];
        bf16x8 x[8];
        #pragma unroll
        for (int i = 0; i < 8; ++i) x[i] = *(const bf16x8*)(xb + (size_t)ew[i].y * 128 + c * 8);
        #pragma unroll
        for (int i = 0; i < 8; ++i) {
            float w = __uint_as_float(ew[i].x);
            #pragma unroll
            for (int j = 0; j < 8; ++j) acc[j] = fmaf(w, bf2f(x[i][j]), acc[j]);
        }
    }
    for (; e + 3 < e1; e += 4) {
        uint2 ew[4];
        #pragma unroll
        for (int i = 0; i < 4; ++i) ew[i] = csr[e + i];
        bf16x8 x[4];
        #pragma unroll
        for (int i = 0; i < 4; ++i) x[i] = *(const bf16x8*)(xb + (size_t)ew[i].y * 128 + c * 8);
        #pragma unroll
        for (int i = 0; i < 4; ++i) {
            float w = __uint_as_float(ew[i].x);
            #pragma unroll
            for (int j = 0; j < 8; ++j) acc[j] = fmaf(w, bf2f(x[i][j]), acc[j]);
        }
    }
    for (; e < e1; ++e) {
        uint2 ew = csr[e];
        float w = __uint_as_float(ew.x);
        bf16x8 x0 = *(const bf16x8*)(xb + (size_t)ew.y * 128 + c * 8);
        #pragma unroll
        for (int j = 0; j < 8; ++j) acc[j] = fmaf(w, bf2f(x0[j]), acc[j]);
    }
}

// count in-degree; record each edge's rank within its dst bucket
__global__ void k_deg(const int* __restrict__ dst, int* __restrict__ degi,
                      unsigned short* __restrict__ rank, int E) {
    int e = blockIdx.x * 256 + threadIdx.x;
    if (e < E) rank[e] = (unsigned short)atomicAdd(&degi[dst[e]], 1);
}

// block sums of degi + fused dinv = rsqrt(deg+1) + degree histogram (for sort)
__global__ void k_scan1(const int* __restrict__ degi, float* __restrict__ dinv,
                        int* __restrict__ blocksum, int* __restrict__ hist, int N) {
    __shared__ int s[256];
    __shared__ int h[256];
    int tid = threadIdx.x;
    h[tid] = 0;
    int i = blockIdx.x * 256 + tid;
    int v = (i < N) ? degi[i] : 0;
    if (i < N) dinv[i] = rsqrtf((float)(v + 1));
    s[tid] = v;
    __syncthreads();
    if (i < N) atomicAdd(&h[v > 255 ? 255 : v], 1);
    for (int st = 128; st > 0; st >>= 1) {
        if (tid < st) s[tid] += s[tid + st];
        __syncthreads();
    }
    if (tid == 0) blocksum[blockIdx.x] = s[0];
    int hv = h[tid];
    if (hv) atomicAdd(&hist[tid], hv);
}

// per-element exclusive scan; every block redundantly scans blocksum in LDS. nb <= 256.
// block 0 additionally exclusive-scans the degree histogram -> histbase.
__global__ void k_scan3(const int* __restrict__ degi, const int* __restrict__ blocksum,
                        int nb, int* __restrict__ rowstart,
                        const int* __restrict__ hist, int* __restrict__ histbase,
                        int N, int E) {
    __shared__ int sb[256];
    __shared__ int s[256];
    int tid = threadIdx.x;
    int bv = (tid < nb) ? blocksum[tid] : 0;
    sb[tid] = bv;
    __syncthreads();
    for (int st = 1; st < 256; st <<= 1) {
        int t = (tid >= st) ? sb[tid - st] : 0;
        __syncthreads();
        sb[tid] += t;
        __syncthreads();
    }
    int boff = (blockIdx.x == 0) ? 0 : sb[blockIdx.x - 1];

    int i = blockIdx.x * 256 + tid;
    int v = (i < N) ? degi[i] : 0;
    s[tid] = v;
    __syncthreads();
    for (int st = 1; st < 256; st <<= 1) {
        int t = (tid >= st) ? s[tid - st] : 0;
        __syncthreads();
        s[tid] += t;
        __syncthreads();
    }
    if (i < N) rowstart[i] = s[tid] - v + boff;
    if (blockIdx.x == 0 && tid == 0) rowstart[N] = E;

    if (blockIdx.x == 0) {
        __shared__ int hh[256];
        int own = hist[tid];
        hh[tid] = own;
        __syncthreads();
        for (int st = 1; st < 256; st <<= 1) {
            int t = (tid >= st) ? hh[tid - st] : 0;
            __syncthreads();
            hh[tid] += t;
            __syncthreads();
        }
        histbase[tid] = hh[tid] - own;   // exclusive
    }
}

// CSR fill with precomputed edge weights (edge blocks) + degree-sort scatter
// (node blocks, two-level counting: LDS rank + 1 global atomic/bucket/block).
__global__ void k_fillperm(const int* __restrict__ src, const int* __restrict__ dst,
                           const unsigned short* __restrict__ rank,
                           const int* __restrict__ rowstart,
                           const float* __restrict__ dinv,
                           uint2* __restrict__ csr,
                           const int* __restrict__ degi,
                           const int* __restrict__ histbase, int* __restrict__ histcnt,
                           int* __restrict__ perm, int E, int N, int nbE) {
    __shared__ int h[256];
    __shared__ int base[256];
    int tid = threadIdx.x;
    if ((int)blockIdx.x < nbE) {
        int e = blockIdx.x * 256 + tid;
        if (e < E) {
            int d = dst[e];
            int s = src[e];
            int pos = rowstart[d] + (int)rank[e];
            uint2 ev;
            ev.x = __float_as_uint(dinv[s] * dinv[d]);
            ev.y = (unsigned)s;
            csr[pos] = ev;
        }
        return;
    }
    int i0 = ((int)blockIdx.x - nbE) * 1024;
    h[tid] = 0;
    __syncthreads();
    int d[4], lr[4];
    #pragma unroll
    for (int k = 0; k < 4; ++k) {
        int i = i0 + k * 256 + tid;
        if (i < N) {
            int dd = degi[i];
            if (dd > 255) dd = 255;
            d[k] = dd;
            lr[k] = atomicAdd(&h[dd], 1);     // LDS atomic: local rank
        } else {
            d[k] = -1;
        }
    }
    __syncthreads();
    int cnt = h[tid];
    if (cnt > 0) base[tid] = atomicAdd(&histcnt[tid], cnt);   // 1 global atomic / bucket / block
    __syncthreads();
    #pragma unroll
    for (int k = 0; k < 4; ++k) {
        if (d[k] >= 0)
            perm[histbase[d[k]] + base[d[k]] + lr[k]] = i0 + k * 256 + tid;
    }
}

// fused prep: W swizzle -> bf16 fragments, features -> bf16, zero degi/stats/hist
__global__ void k_prep(const float* __restrict__ W1, const float* __restrict__ W2,
                       short* __restrict__ W1sw, short* __restrict__ W2sw,
                       const float4* __restrict__ nf, short4* __restrict__ nfb,
                       int* __restrict__ degi, float* __restrict__ stats,
                       int* __restrict__ hist, int n4, int N) {
    int t = blockIdx.x * 256 + threadIdx.x;
    if (t < 32768) {                 // W1 [128][256]
        if (t < 512) stats[t] = 0.0f;
        else if (t < 1024) hist[t - 512] = 0;   // hist[256] ++ histcnt[256]
        int n = t >> 7, kk = t & 127;
        float v = W1[kk * 256 + n];
        int t16 = n >> 4, m = n & 15;
        int ks = kk >> 5, q = (kk >> 3) & 3, j = kk & 7;
        W1sw[(t16 * 4 + ks) * 512 + (q * 16 + m) * 8 + j] = f2bf(v);
    } else if (t < 65536) {          // W2 [256][128]
        int u = t - 32768;
        int n = u >> 8, kk = u & 255;
        float v = W2[kk * 128 + n];
        int t16 = n >> 4, m = n & 15;
        int ks = kk >> 5, q = (kk >> 3) & 3, j = kk & 7;
        W2sw[(t16 * 8 + ks) * 512 + (q * 16 + m) * 8 + j] = f2bf(v);
    } else {
        int u = t - 65536;
        if (u < n4) {
            float4 v = nf[u];
            short4 s;
            s.x = f2bf(v.x); s.y = f2bf(v.y); s.z = f2bf(v.z); s.w = f2bf(v.w);
            nfb[u] = s;
        } else {
            int u2 = u - n4;
            if (u2 < N) degi[u2] = 0;
        }
    }
}

// Layer 1 fused: gather(S @ nfb) for 64 rows straight into the LDS A-tile,
// then x1 = A @ W1 + b1 with BN-stat accumulation via atomics.
// FOLD assignment: block b gets heavy chunk (descending ranks [32b,32b+32),
// pass 0) + light chunk (ascending-from-bottom ranks [32b,32b+32), pass 1).
//  - within a pass all 32 concurrent rows are rank-adjacent -> equal degree
//    (no wave imbalance, no lockstep divergence)
//  - per-THREAD total = Q_top(32b)+Q_bot(32b) ~ 2*mean, flat across blocks
//    (no barrier between passes -> per-thread sum is the binding quantity)
//  - 2*32*nb slots vs M rows: the 2*HALF-M middle rows appear twice as the
//    SAME perm element -> bit-identical C writes (benign); BN stats exclude
//    the duplicate via light_rank < M-HALF.
__global__ __launch_bounds__(512, 4) void k_gemm1g(
        const short* __restrict__ xb, const int* __restrict__ rowstart,
        const uint2* __restrict__ csr, const float* __restrict__ dinv,
        const int* __restrict__ perm, const short* __restrict__ Bsw,
        const float* __restrict__ bias, short* __restrict__ C,
        float* __restrict__ stats, int M) {
    constexpr int K = CIN, NOUT = CH;
    constexpr int CT = NOUT / 128;   // 2 col16-tiles per wave (8 waves)
    constexpr int KS = K / 32;       // 4
    constexpr int KP = K + 8;
    constexpr int LROW = NOUT + 8;
    constexpr int LSZ = (64 * KP > 64 * LROW) ? 64 * KP : 64 * LROW;
    __shared__ __align__(16) short lds[LSZ];
    __shared__ int prow[64];
    int tid = threadIdx.x;
    int wave = tid >> 6;             // 0..7
    int lane = tid & 63;
    int m = lane & 15;
    int q = lane >> 4;
    int nb = gridDim.x;
    int bid = blockIdx.x;
    int lightN = M - 32 * nb;        // light ranks < lightN are unique (not dups)
    if (tid < 64) {
        int row;
        if (tid < 32) {
            row = perm[M - 1 - (bid * 32 + tid)];   // heavy: rank from top
        } else {
            row = perm[bid * 32 + (tid - 32)];      // light: rank from bottom
        }
        prow[tid] = row;
    }
    __syncthreads();

    // gather phase: pass 0 = heavy rows, pass 1 = light rows
    int c = tid & 15;
    int g = tid >> 4;                // 0..31
    #pragma unroll
    for (int p = 0; p < 2; ++p) {
        int rl = p * 32 + g;
        int r = prow[rl];
        float di = dinv[r];
        float w0 = di * di;
        bf16x8 sv = *(const bf16x8*)(xb + (size_t)r * 128 + c * 8);
        float acc[8];
        #pragma unroll
        for (int j = 0; j < 8; ++j) acc[j] = bf2f(sv[j]) * w0;
        gather_edges(xb, csr, rowstart[r], rowstart[r + 1], c, acc);
        bf16x8 h;
        #pragma unroll
        for (int j = 0; j < 8; ++j) h[j] = f2bf(acc[j]);
        *(bf16x8*)(lds + rl * KP + c * 8) = h;
    }
    __syncthreads();

    f32x4 acc4[4][CT];
    #pragma unroll
    for (int rt = 0; rt < 4; ++rt)
        #pragma unroll
        for (int ct = 0; ct < CT; ++ct)
            acc4[rt][ct] = (f32x4){0.f, 0.f, 0.f, 0.f};

    #pragma unroll
    for (int ks = 0; ks < KS; ++ks) {
        bf16x8 bh[CT];
        #pragma unroll
        for (int ct = 0; ct < CT; ++ct)
            bh[ct] = *(const bf16x8*)(Bsw + (size_t)((wave * CT + ct) * KS + ks) * 512 + lane * 8);
        bf16x8 af[4];
        #pragma unroll
        for (int rt = 0; rt < 4; ++rt)
            af[rt] = *(const bf16x8*)(lds + (rt * 16 + m) * KP + ks * 32 + q * 8);
        #pragma unroll
        for (int ct = 0; ct < CT; ++ct)
            #pragma unroll
            for (int rt = 0; rt < 4; ++rt)
                acc4[rt][ct] = __builtin_amdgcn_mfma_f32_16x16x32_bf16(af[rt], bh[ct], acc4[rt][ct], 0, 0, 0);
    }
    __syncthreads();   // A-tile reads done; reuse LDS for epilogue

    #pragma unroll
    for (int ct = 0; ct < CT; ++ct) {
        int col = wave * 32 + ct * 16 + m;
        float bv = bias[col];
        float s = 0.f, sq = 0.f;
        #pragma unroll
        for (int rt = 0; rt < 4; ++rt) {
            #pragma unroll
            for (int r = 0; r < 4; ++r) {
                int lrow = rt * 16 + q * 4 + r;
                float v = acc4[rt][ct][r] + bv;
                // heavy rows always counted; light rows counted unless dup
                bool cnt = (lrow < 32) || (bid * 32 + lrow - 32 < lightN);
                if (cnt) { s += v; sq = fmaf(v, v, sq); }
                lds[lrow * LROW + col] = f2bf(v);
            }
        }
        s += __shfl_xor(s, 16, 64);
        s += __shfl_xor(s, 32, 64);
        sq += __shfl_xor(sq, 16, 64);
        sq += __shfl_xor(sq, 32, 64);
        if (lane < 16) {
            unsafeAtomicAdd(&stats[col], s);
            unsafeAtomicAdd(&stats[256 + col], sq);
        }
    }
    __syncthreads();
    constexpr int CPR = NOUT / 8;       // 32
    #pragma unroll
    for (int i = 0; i < (64 * CPR) / 512; ++i) {
        int idx = i * 512 + tid;
        int row = idx / CPR;
        int ch = idx % CPR;
        // every slot maps to a valid row; dup rows write identical bytes
        *(bf16x8*)(C + (size_t)prow[row] * NOUT + ch * 8) =
            *(const bf16x8*)(lds + row * LROW + ch * 8);
    }
}

__device__ __forceinline__ bf16x8 bnrelu8(bf16x8 raw, const float* __restrict__ scsh, int c) {
    float4 sc0 = *(const float4*)(scsh + c);
    float4 sc1 = *(const float4*)(scsh + c + 4);
    float4 sh0 = *(const float4*)(scsh + 256 + c);
    float4 sh1 = *(const float4*)(scsh + 256 + c + 4);
    bf16x8 o;
    o[0] = f2bf(fmaxf(fmaf(bf2f(raw[0]), sc0.x, sh0.x), 0.f));
    o[1] = f2bf(fmaxf(fmaf(bf2f(raw[1]), sc0.y, sh0.y), 0.f));
    o[2] = f2bf(fmaxf(fmaf(bf2f(raw[2]), sc0.z, sh0.z), 0.f));
    o[3] = f2bf(fmaxf(fmaf(bf2f(raw[3]), sc0.w, sh0.w), 0.f));
    o[4] = f2bf(fmaxf(fmaf(bf2f(raw[4]), sc1.x, sh1.x), 0.f));
    o[5] = f2bf(fmaxf(fmaf(bf2f(raw[5]), sc1.y, sh1.y), 0.f));
    o[6] = f2bf(fmaxf(fmaf(bf2f(raw[6]), sc1.z, sh1.z), 0.f));
    o[7] = f2bf(fmaxf(fmaf(bf2f(raw[7]), sc1.w, sh1.w), 0.f));
    return o;
}

// Layer 2 GEMM: y = relu(bn(x1)) @ W2. BN scale/shift derived from stats in
// each block (2KB LDS, trivial redundant compute).
__global__ __launch_bounds__(256, 4) void k_gemm2(
        const short* __restrict__ A, const short* __restrict__ Bsw,
        const float* __restrict__ stats, const float* __restrict__ gamma,
        const float* __restrict__ beta, short* __restrict__ C, int M) {
    constexpr int K = CH, NOUT = COUT;
    constexpr int CT = NOUT / 64;    // 2
    constexpr int KS = K / 32;       // 8
    constexpr int KP = K + 8;
    constexpr int LROW = NOUT + 8;
    constexpr int LSZ = (64 * KP > 64 * LROW) ? 64 * KP : 64 * LROW;
    __shared__ __align__(16) short lds[LSZ];
    __shared__ float scsh[512];
    int tid = threadIdx.x;
    int wave = tid >> 6;
    int lane = tid & 63;
    int m = lane & 15;
    int q = lane >> 4;
    int row0 = blockIdx.x * 64;

    if (tid < 256) {
        float invN = 1.0f / (float)M;
        float mean = stats[tid] * invN;
        float var = fmaxf(stats[256 + tid] * invN - mean * mean, 0.f);
        float inv = rsqrtf(var + BN_EPS);
        float sc = gamma[tid] * inv;
        scsh[tid] = sc;
        scsh[256 + tid] = fmaf(-mean, sc, beta[tid]);
    }
    __syncthreads();

    constexpr int CPRA = K / 8;      // 32
    #pragma unroll
    for (int i = 0; i < (64 * CPRA) / 256; ++i) {
        int idx = i * 256 + tid;
        int r = idx / CPRA, cc = idx % CPRA;
        int gr = row0 + r;
        if (gr >= M) gr = M - 1;
        bf16x8 v = *(const bf16x8*)(A + (size_t)gr * K + cc * 8);
        v = bnrelu8(v, scsh, cc * 8);
        *(bf16x8*)(lds + r * KP + cc * 8) = v;
    }
    __syncthreads();

    f32x4 acc[4][CT];
    #pragma unroll
    for (int rt = 0; rt < 4; ++rt)
        #pragma unroll
        for (int ct = 0; ct < CT; ++ct)
            acc[rt][ct] = (f32x4){0.f, 0.f, 0.f, 0.f};

    #pragma unroll
    for (int ks = 0; ks < KS; ++ks) {
        bf16x8 bh[CT];
        #pragma unroll
        for (int ct = 0; ct < CT; ++ct)
            bh[ct] = *(const bf16x8*)(Bsw + (size_t)((wave * CT + ct) * KS + ks) * 512 + lane * 8);
        bf16x8 af[4];
        #pragma unroll
        for (int rt = 0; rt < 4; ++rt)
            af[rt] = *(const bf16x8*)(lds + (rt * 16 + m) * KP + ks * 32 + q * 8);
        #pragma unroll
        for (int ct = 0; ct < CT; ++ct)
            #pragma unroll
            for (int rt = 0; rt < 4; ++rt)
                acc[rt][ct] = __builtin_amdgcn_mfma_f32_16x16x32_bf16(af[rt], bh[ct], acc[rt][ct], 0, 0, 0);
    }
    __syncthreads();

    #pragma unroll
    for (int ct = 0; ct < CT; ++ct) {
        int col = wave * (NOUT / 4) + ct * 16 + m;
        #pragma unroll
        for (int rt = 0; rt < 4; ++rt) {
            #pragma unroll
            for (int r = 0; r < 4; ++r) {
                int lrow = rt * 16 + q * 4 + r;
                lds[lrow * LROW + col] = f2bf(acc[rt][ct][r]);
            }
        }
    }
    __syncthreads();
    constexpr int CPR = NOUT / 8;    // 16
    #pragma unroll
    for (int i = 0; i < (64 * CPR) / 256; ++i) {
        int idx = i * 256 + tid;
        int row = idx / CPR;
        int ch = idx % CPR;
        if (row0 + row < M)
            *(bf16x8*)(C + (size_t)(row0 + row) * NOUT + ch * 8) =
                *(const bf16x8*)(lds + row * LROW + ch * 8);
    }
}

// final gather: out = S @ y + b2, fp32 output, degree-sorted row order
// (3125 blocks, descending degree = SPT schedule; many rounds -> balanced)
__global__ __launch_bounds__(256) void k_gather1(
        const short* __restrict__ yb, const int* __restrict__ rowstart,
        const uint2* __restrict__ csr, const float* __restrict__ dinv,
        const int* __restrict__ perm, const float* __restrict__ bias,
        float* __restrict__ out, int N) {
    int t = blockIdx.x * 256 + threadIdx.x;
    int sp = t >> 4;
    int c = t & 15;
    if (sp >= N) return;
    int r = perm[N - 1 - sp];        // descending degree
    float di = dinv[r];
    float w0 = di * di;
    bf16x8 sv = *(const bf16x8*)(yb + (size_t)r * 128 + c * 8);
    float acc[8];
    #pragma unroll
    for (int j = 0; j < 8; ++j) acc[j] = bf2f(sv[j]) * w0;
    gather_edges(yb, csr, rowstart[r], rowstart[r + 1], c, acc);
    float4 b0 = *(const float4*)(bias + c * 8);
    float4 b1 = *(const float4*)(bias + c * 8 + 4);
    float4 o0 = make_float4(acc[0] + b0.x, acc[1] + b0.y, acc[2] + b0.z, acc[3] + b0.w);
    float4 o1 = make_float4(acc[4] + b1.x, acc[5] + b1.y, acc[6] + b1.z, acc[7] + b1.w);
    *(float4*)(out + (size_t)r * 128 + c * 8) = o0;
    *(float4*)(out + (size_t)r * 128 + c * 8 + 4) = o1;
}

extern "C" void kernel_launch(void* const* d_in, const int* in_sizes, int n_in,
                              void* d_out, int out_size, void* d_ws, size_t ws_size,
                              hipStream_t stream) {
    const float* nf    = (const float*)d_in[0];
    const int*   ei    = (const int*)d_in[1];
    const float* W1    = (const float*)d_in[2];
    const float* b1    = (const float*)d_in[3];
    const float* gamma = (const float*)d_in[4];
    const float* beta  = (const float*)d_in[5];
    const float* W2    = (const float*)d_in[6];
    const float* b2    = (const float*)d_in[7];
    float* out = (float*)d_out;

    const int N = in_sizes[0] / CIN;      // 50000
    const int E = in_sizes[1] / 2;        // 800000
    const int* src = ei;
    const int* dst = ei + E;

    const int nb1 = (N + 63) / 64;        // gemm row-blocks (782)

    char* ws = (char*)d_ws;
    auto align256 = [](size_t x) { return (x + 255) & ~(size_t)255; };
    size_t off = 0;
    int*   degi = (int*)(ws + off);      off += align256((size_t)N * 4);
    float* stats = (float*)(ws + off);   off += align256(512 * 4);
    float* dinv = (float*)(ws + off);    off += align256((size_t)N * 4);
    int*   rowstart = (int*)(ws + off);  off += align256((size_t)(N + 1) * 4);
    int*   blocksum = (int*)(ws + off);  off += align256(256 * 4);
    int*   hist = (int*)(ws + off);      off += align256(512 * 4);    // hist + histcnt
    int*   histbase = (int*)(ws + off);  off += align256(256 * 4);
    int*   perm = (int*)(ws + off);      off += align256((size_t)N * 4);
    short* W1sw = (short*)(ws + off);    off += align256(32768 * 2);
    short* W2sw = (short*)(ws + off);    off += align256(32768 * 2);
    unsigned short* rank = (unsigned short*)(ws + off); off += align256((size_t)E * 2);
    uint2* csr = (uint2*)(ws + off);     off += align256((size_t)E * 8);   // packed {w, src}
    short* nfb = (short*)(ws + off);     off += align256((size_t)N * CIN * 2);
    short* x1b = (short*)(ws + off);     off += align256((size_t)N * CH * 2);
    short* yb = (short*)(ws + off);      off += align256((size_t)N * COUT * 2);

    int nbN = (N + 255) / 256;
    int nbE = (E + 255) / 256;            // 3125 (E % 256 == 0)
    int nbP = (N + 1023) / 1024;          // 49 node-blocks for perm build
    int n4 = N * 32;

    // prep: weight swizzle + feature cast + zero degi/stats/hist
    k_prep<<<(65536 + n4 + N + 255) / 256, 256, 0, stream>>>(
        W1, W2, W1sw, W2sw, (const float4*)nf, (short4*)nfb, degi, stats, hist, n4, N);

    // degree/rank -> dinv + histogram -> rowstart + histbase -> CSR fill + perm
    k_deg<<<nbE, 256, 0, stream>>>(dst, degi, rank, E);
    k_scan1<<<nbN, 256, 0, stream>>>(degi, dinv, blocksum, hist, N);
    k_scan3<<<nbN, 256, 0, stream>>>(degi, blocksum, nbN, rowstart, hist, histbase, N, E);
    k_fillperm<<<nbE + nbP, 256, 0, stream>>>(
        src, dst, rank, rowstart, dinv, csr, degi, histbase, hist + 256, perm, E, N, nbE);

    // layer 1: fused gather + GEMM + bias + BN-stat atomics (fold balance)
    k_gemm1g<<<nb1, 512, 0, stream>>>(nfb, rowstart, csr, dinv, perm, W1sw, b1, x1b, stats, N);

    // layer 2: BN+ReLU (inline from stats) + GEMM
    k_gemm2<<<nb1, 256, 0, stream>>>(x1b, W2sw, stats, gamma, beta, yb, N);

    // out = S @ y + b2
    k_gather1<<<(N * 16 + 255) / 256, 256, 0, stream>>>(
        yb, rowstart, csr, dinv, perm, b2, out, N);
}